// Round 7
// baseline (123.068 us; speedup 1.0000x reference)
//
#include <hip/hip_runtime.h>
#include <stdint.h>

// Problem constants (from reference)
#define BATCH 1024
#define FEAT  784
#define OUTF  1024
#define OR_T  32
#define AND_T 16
#define NIDX  1569          // 1 + 2*FEAT boolean input columns
#define BSTRIDE 1600        // padded u64 words per batch-group bit column
#define NGROUP  16          // BATCH / 64
#define TKDIM   512         // OR_T * AND_T flattened (term,k) extent
#define WPAD    257         // padded u32 row stride for widx[o][tk/2]
#define NUNIT   3136        // 16 groups x 196 float4-column pack units

#define RDY_OFF ((size_t)NGROUP * BSTRIDE * 8)   // 204,800
#define WS_NEED (RDY_OFF + (size_t)NUNIT * 4)    // 217,344 B

// Distinct-byte magic: cannot be produced by any repeated-byte poison fill.
#define MAGIC   0x1B9D5E63

typedef unsigned long long u64;

// ---------------------------------------------------------------------------
// Single ordinary-launch kernel; cross-block ordering via agent-scope
// atomics only (no grid.sync -> no per-block L2 invalidation storms).
//
// 1024 blocks x 256 threads; LDS 31.3 KB -> 5 blocks/CU co-residency
// capacity (1280 >= 1024: all blocks resident, spin is deadlock-free; a
// bounded spin + local-recompute fallback guarantees termination anyway).
//
// Each block:
//  produce: wave-unit u = wv*1024+bid (<3136): scattered float4 of x,
//    4 ballots, agent-relaxed u64 stores into bits[pg] (L3-coherent),
//    then a RELEASE agent store of MAGIC to ready[u]. Every block
//    produces BEFORE it consumes -> no ordering assumption on dispatch.
//  stage widx: verified fused2/eval4 staging of the block's contiguous
//    32 KB natural-layout w slice into LDS u16 pairs (pad 257, 2-way).
//    Issued before the spin so the L2 reads overlap other blocks' packs.
//  spin: wait for the 196 ready flags of group g (relaxed agent loads +
//    __syncthreads_and). Exits ~2-3 us after launch in practice.
//  lbits: 1600 agent-relaxed u64 loads (L3-hot, just written).
//  eval: byte-identical verified core (2 OR-terms/thread, or_mask via
//    zor, LDS OR-reduce over 16 term-groups, 4 coalesced int32 stores).
// ---------------------------------------------------------------------------
__global__ __launch_bounds__(256) void fusedspin(const float* __restrict__ x,
                                                 const int* __restrict__ w,
                                                 u64* __restrict__ bits,
                                                 int* __restrict__ ready,
                                                 int* __restrict__ out) {
    __shared__ u64 lbits[BSTRIDE];                 // 12.8 KB
    __shared__ unsigned int widx[16 * WPAD];       // 16.4 KB
    __shared__ u64 red[256];                       // 2 KB

    const int bid  = blockIdx.x;
    const int tid  = threadIdx.x;
    const int lane = tid & 63;
    const int wv   = tid >> 6;               // wave 0..3

    const int xcd = bid & 7;
    const int s   = bid >> 3;                // 0..127
    const int ob  = xcd + 8 * (s & 1);       // 0..15, 2 per XCD (w L2-hot)
    const int q   = (s >> 1) & 3;            // quarter 0..3
    const int g   = s >> 3;                  // 0..15

    // ---- produce: one pack unit per wave (3136 active of 4096 slots) ----
    const int u = wv * 1024 + bid;
    if (u < NUNIT) {
        const int pg = u / 196;              // batch group 0..15
        const int f4 = u % 196;              // float4 column-group
        const float4 v = *(const float4*)(x + (size_t)(pg * 64 + lane) * FEAT
                                            + f4 * 4);
        u64* bg = bits + (size_t)pg * BSTRIDE;
        const u64 m0 = __ballot(v.x != 0.0f);
        const u64 m1 = __ballot(v.y != 0.0f);
        const u64 m2 = __ballot(v.z != 0.0f);
        const u64 m3 = __ballot(v.w != 0.0f);
        const u64 mv = (lane == 0) ? m0 : (lane == 1) ? m1 : (lane == 2) ? m2 : m3;
        const int f = f4 * 4;
        if (lane < 4) {
            __hip_atomic_store(&bg[1 + f + lane], mv,
                               __ATOMIC_RELAXED, __HIP_MEMORY_SCOPE_AGENT);
            __hip_atomic_store(&bg[785 + f + lane], ~mv,
                               __ATOMIC_RELAXED, __HIP_MEMORY_SCOPE_AGENT);
        }
        if (f4 == 0 && lane == 4) {
            __hip_atomic_store(&bg[0], ~0ull,
                               __ATOMIC_RELAXED, __HIP_MEMORY_SCOPE_AGENT);
        }
        if (lane == 0) {
            // release orders the wave's prior data stores before the flag
            __hip_atomic_store(&ready[u], (int)MAGIC,
                               __ATOMIC_RELEASE, __HIP_MEMORY_SCOPE_AGENT);
        }
    }

    // ---- stage widx: 32 KB contiguous w slice -> LDS u16 pairs ----
    const int4* wsrc = (const int4*)(w + (size_t)(ob * 64 + q * 16) * TKDIM);
    #pragma unroll
    for (int t = 0; t < 8; ++t) {
        const int q4 = t * 256 + tid;        // int4 index 0..2047
        const int4 v = wsrc[q4];
        const int o  = q4 >> 7;              // output row 0..15 (128 int4/row)
        const int r  = (q4 & 127) * 2;       // packed-pair index (even)
        widx[o * WPAD + r] =
            ((unsigned int)v.x & 0xFFFFu) | ((unsigned int)v.y << 16);
        widx[o * WPAD + r + 1] =
            ((unsigned int)v.z & 0xFFFFu) | ((unsigned int)v.w << 16);
    }

    // ---- spin: wait for group's 196 pack units (bounded) ----
    const int* rg = ready + g * 196;
    int ok = (tid < 196) ? 0 : 1;
    int alldone = 0;
    for (int it = 0; it < 200000 && !alldone; ++it) {
        if (!ok && __hip_atomic_load(&rg[tid], __ATOMIC_RELAXED,
                                     __HIP_MEMORY_SCOPE_AGENT) == (int)MAGIC)
            ok = 1;
        alldone = __syncthreads_and(ok);
    }

    if (alldone) {
        // ---- stage lbits from L3 (agent loads match the agent stores) ----
        const u64* bg2 = bits + (size_t)g * BSTRIDE;
        #pragma unroll
        for (int i = 0; i < 7; ++i) {
            const int t = i * 256 + tid;
            if (t < BSTRIDE)
                lbits[t] = __hip_atomic_load(&bg2[t], __ATOMIC_RELAXED,
                                             __HIP_MEMORY_SCOPE_AGENT);
        }
    } else {
        // ---- fallback (never expected): recompute table locally ----
        for (int i = 0; i < 49; ++i) {
            const int f4 = wv * 49 + i;      // 4 waves x 49 = 196 columns
            const float4 v = *(const float4*)(x + (size_t)(g * 64 + lane) * FEAT
                                                + f4 * 4);
            const u64 m0 = __ballot(v.x != 0.0f);
            const u64 m1 = __ballot(v.y != 0.0f);
            const u64 m2 = __ballot(v.z != 0.0f);
            const u64 m3 = __ballot(v.w != 0.0f);
            const u64 mv = (lane == 0) ? m0 : (lane == 1) ? m1
                         : (lane == 2) ? m2 : m3;
            const int f = f4 * 4;
            if (lane < 4) {
                lbits[1 + f + lane]   = mv;
                lbits[785 + f + lane] = ~mv;
            }
        }
        if (tid == 0) lbits[0] = ~0ull;
    }
    __syncthreads();

    // ---- eval: 2 OR-terms per thread (verified fusedc/eval4 core) ----
    const int ol = tid & 15;
    const int tg = tid >> 4;                 // term-group 0..15

    u64 orv = 0;
    #pragma unroll
    for (int tt = 0; tt < 2; ++tt) {
        const int term = tg * 2 + tt;
        const unsigned int* wr = widx + ol * WPAD + term * 8;
        u64 a = ~0ull;
        unsigned int zor = 0;                // OR of the 16 indices (or_mask)
        #pragma unroll
        for (int kk = 0; kk < 8; ++kk) {
            const unsigned int pk = wr[kk];
            zor |= pk;
            a &= lbits[pk & 0xFFFFu];
            a &= lbits[pk >> 16];
        }
        if (zor != 0) orv |= a;              // all-zero term is masked off
    }

    red[tid] = orv;
    __syncthreads();

    u64 full = 0;
    #pragma unroll
    for (int j = 0; j < 16; ++j) full |= red[j * 16 + ol];

    int* outg = out + (size_t)(g * 64) * OUTF + (size_t)ob * 64 + q * 16;
    #pragma unroll
    for (int jj = 0; jj < 4; ++jj) {
        const int j = tg * 4 + jj;
        outg[(size_t)j * OUTF + ol] = (int)((full >> j) & 1);
    }
}

// ---------------------------------------------------------------------------
// Fallback: fully fused per-block if ws is too small. Verified baseline math.
// ---------------------------------------------------------------------------
__global__ __launch_bounds__(1024) void binlayer_fused(const float* __restrict__ x,
                                                       const int* __restrict__ w,
                                                       int* __restrict__ out) {
    __shared__ u64 lbits[BSTRIDE];
    __shared__ u64 red[1024];

    const int g    = blockIdx.x;
    const int ob   = blockIdx.y;
    const int tid  = threadIdx.x;
    const int lane = tid & 63;
    const int wv   = tid >> 6;

    const int start = wv * 12 + (wv < 4 ? wv : 4);
    const int cnt   = (wv < 4) ? 13 : 12;
    const float4* xrow = (const float4*)(x + (size_t)(g * 64 + lane) * FEAT);
    for (int i = 0; i < cnt; ++i) {
        const int f4 = start + i;
        const float4 v = xrow[f4];
        const int f = f4 * 4;
        const u64 m0 = __ballot(v.x != 0.0f);
        const u64 m1 = __ballot(v.y != 0.0f);
        const u64 m2 = __ballot(v.z != 0.0f);
        const u64 m3 = __ballot(v.w != 0.0f);
        const u64 mv = (lane == 0) ? m0 : (lane == 1) ? m1 : (lane == 2) ? m2 : m3;
        if (lane < 4) {
            lbits[1 + f + lane]   = mv;
            lbits[785 + f + lane] = ~mv;
        }
    }
    if (tid == 0) lbits[0] = ~0ull;
    __syncthreads();

    const int o_local = tid & 63;
    const int tg      = tid >> 6;
    const int o       = ob * 64 + o_local;
    const int4* wq = (const int4*)(w + ((size_t)o * OR_T + tg * 2) * AND_T);

    u64 orv = 0;
    #pragma unroll
    for (int tt = 0; tt < 2; ++tt) {
        u64 a = ~0ull;
        int zor = 0;
        #pragma unroll
        for (int k = 0; k < 4; ++k) {
            const int4 wi = wq[tt * 4 + k];
            zor |= wi.x | wi.y | wi.z | wi.w;
            a &= lbits[wi.x];
            a &= lbits[wi.y];
            a &= lbits[wi.z];
            a &= lbits[wi.w];
        }
        if (zor != 0) orv |= a;
    }

    red[tid] = orv;
    __syncthreads();

    u64 full = 0;
    #pragma unroll
    for (int j = 0; j < 16; ++j) full |= red[o_local + j * 64];

    int* outg = out + (size_t)(g * 64) * OUTF + (size_t)ob * 64;
    #pragma unroll
    for (int jj = 0; jj < 4; ++jj) {
        const int j = tg * 4 + jj;
        outg[(size_t)j * OUTF + o_local] = (int)((full >> j) & 1);
    }
}

extern "C" void kernel_launch(void* const* d_in, const int* in_sizes, int n_in,
                              void* d_out, int out_size, void* d_ws, size_t ws_size,
                              hipStream_t stream) {
    (void)in_sizes; (void)n_in;
    const float* x = (const float*)d_in[0];   // (1024, 784) float32 of 0/1
    const int*   w = (const int*)d_in[1];     // (1024, 32, 16) int32 in [0,1569)
    int* out = (int*)d_out;                   // (1024, 1024) bool -> int32

    if (ws_size >= WS_NEED) {
        u64* bits  = (u64*)d_ws;
        int* ready = (int*)((char*)d_ws + RDY_OFF);
        fusedspin<<<1024, 256, 0, stream>>>(x, w, bits, ready, out);
    } else {
        binlayer_fused<<<dim3(NGROUP, OUTF / 64), 1024, 0, stream>>>(x, w, out);
    }
}

// Round 8
// 70.957 us; speedup vs baseline: 1.7344x; 1.7344x over previous
//
#include <hip/hip_runtime.h>
#include <stdint.h>

// Problem constants (from reference)
#define BATCH 1024
#define FEAT  784
#define OUTF  1024
#define OR_T  32
#define AND_T 16
#define NIDX  1569          // 1 + 2*FEAT boolean input columns
#define NGROUP  16          // BATCH / 64
#define TKDIM   512         // OR_T * AND_T flattened (term,k) extent
#define WPAD    257         // padded u32 row stride for widx[o][tk/2]
#define NIBROW  204         // padded u8 row stride for nibble tile (51 dw, odd)

typedef unsigned long long u64;

// ---------------------------------------------------------------------------
// Single ordinary kernel, no workspace, no cross-block communication
// (R5/R7 measured grid.sync ~150us and agent-flag spin ~60us -- both dead).
//
// 512 blocks x 512 threads; block (g, obh) = batch-group g (64 rows) x
// 32 outputs. LDS 62.8 KB -> 2 blocks/CU (16 waves/CU: co-resident blocks
// overlap each other's barriers/loads -- fused3's missing ingredient).
//
//  phase 1: x slice (64 rows x 196 float4) loaded COALESCED (consecutive
//    tid -> consecutive float4 in a row), packed to 4-bit nibbles in a
//    padded u8 tile. One pass, no chunking (fused3 had 13 barriers).
//  phase 2: w slice (32 outputs x 512 ints, 64 KB contiguous) staged as
//    verified u16-pair LDS layout widx[o][tk/2], pad 257.
//  barrier. phase 3: ballots -- wave wv handles tile columns c=i*8+wv;
//    lane=row reads nib[lane*204+c] (51-dword stride, odd -> 2-way, free);
//    4 ballots per column; lanes 0..3 store lbits[1+f]/lbits[785+f] pairs.
//  barrier. phase 4: verified eval core widened to 32 outputs: thread
//    (tg, ol): 2 terms, 16 widx reads (ol*257 stride -> 2-way free) + 32
//    lbits gathers, zor or_mask; red[512] OR-reduce; 4 coalesced stores.
// ---------------------------------------------------------------------------
__global__ __launch_bounds__(512) void fused5(const float* __restrict__ x,
                                              const int* __restrict__ w,
                                              int* __restrict__ out) {
    __shared__ u64 lbits[1600];                    // 12.8 KB
    __shared__ unsigned int widx[32 * WPAD];       // 32.9 KB
    __shared__ unsigned char nib[64 * NIBROW];     // 13.1 KB
    __shared__ u64 red[512];                       // 4 KB   (total 62.8 KB)

    const int bid  = blockIdx.x;
    const int xcd  = bid & 7;
    const int s    = bid >> 3;               // 0..63
    const int g    = xcd * 2 + (s & 1);      // 2 groups per XCD (x L2-hot)
    const int obh  = s >> 1;                 // 0..31 (32-output chunk)
    const int tid  = threadIdx.x;            // 0..511
    const int lane = tid & 63;
    const int wv   = tid >> 6;               // wave 0..7

    // ---- phase 1: x -> nibble tile, coalesced ----
    const float* xg = x + (size_t)(g * 64) * FEAT;
    #pragma unroll
    for (int i = 0; i < 25; ++i) {
        const int idx = i * 512 + tid;       // 12544 active of 12800
        if (idx < 12544) {                   // last iter: waves 0..3 only
            const int r = idx / 196;         // row 0..63 (magic-mul)
            const int c = idx - r * 196;     // float4 col 0..195
            const float4 v = *(const float4*)(xg + (size_t)r * FEAT + c * 4);
            nib[r * NIBROW + c] = (unsigned char)((v.x != 0.0f ? 1u : 0u)
                                                | (v.y != 0.0f ? 2u : 0u)
                                                | (v.z != 0.0f ? 4u : 0u)
                                                | (v.w != 0.0f ? 8u : 0u));
        }
    }

    // ---- phase 2: stage w slice -> LDS u16 pairs (verified packing) ----
    const int4* wsrc = (const int4*)(w + (size_t)(obh * 32) * TKDIM);
    #pragma unroll
    for (int t = 0; t < 8; ++t) {
        const int q4 = t * 512 + tid;        // int4 index 0..4095
        const int4 v = wsrc[q4];
        const int o  = q4 >> 7;              // output row 0..31 (128 int4/row)
        const int r  = (q4 & 127) * 2;       // packed-pair index (even)
        widx[o * WPAD + r] =
            ((unsigned int)v.x & 0xFFFFu) | ((unsigned int)v.y << 16);
        widx[o * WPAD + r + 1] =
            ((unsigned int)v.z & 0xFFFFu) | ((unsigned int)v.w << 16);
    }
    __syncthreads();

    // ---- phase 3: ballots from the tile (lane = batch row) ----
    #pragma unroll
    for (int i = 0; i < 25; ++i) {
        const int c = i * 8 + wv;            // column 0..199; 196 active
        if (c < 196) {                       // wave-uniform predicate
            const unsigned int nv = nib[lane * NIBROW + c];
            const u64 m0 = __ballot((nv & 1u) != 0u);
            const u64 m1 = __ballot((nv & 2u) != 0u);
            const u64 m2 = __ballot((nv & 4u) != 0u);
            const u64 m3 = __ballot((nv & 8u) != 0u);
            const u64 mv = (lane == 0) ? m0 : (lane == 1) ? m1
                         : (lane == 2) ? m2 : m3;
            const int f = c * 4;
            if (lane < 4) {
                lbits[1 + f + lane]   = mv;
                lbits[785 + f + lane] = ~mv;
            }
        }
    }
    if (tid == 0) lbits[0] = ~0ull;
    __syncthreads();

    // ---- phase 4: eval, 2 OR-terms per thread (verified core, 32-wide) ----
    const int ol = tid & 31;                 // output 0..31
    const int tg = tid >> 5;                 // term-group 0..15

    u64 orv = 0;
    #pragma unroll
    for (int tt = 0; tt < 2; ++tt) {
        const int term = tg * 2 + tt;
        const unsigned int* wr = widx + ol * WPAD + term * 8;
        u64 a = ~0ull;
        unsigned int zor = 0;                // OR of the 16 indices (or_mask)
        #pragma unroll
        for (int kk = 0; kk < 8; ++kk) {
            const unsigned int pk = wr[kk];
            zor |= pk;
            a &= lbits[pk & 0xFFFFu];
            a &= lbits[pk >> 16];
        }
        if (zor != 0) orv |= a;              // all-zero term is masked off
    }

    red[tid] = orv;                          // red[tg*32 + ol]
    __syncthreads();

    u64 full = 0;
    #pragma unroll
    for (int j = 0; j < 16; ++j) full |= red[j * 32 + ol];

    int* outg = out + (size_t)(g * 64) * OUTF + (size_t)obh * 32;
    #pragma unroll
    for (int jj = 0; jj < 4; ++jj) {
        const int j = tg * 4 + jj;           // batch-row bit 0..63
        outg[(size_t)j * OUTF + ol] = (int)((full >> j) & 1);
    }
}

extern "C" void kernel_launch(void* const* d_in, const int* in_sizes, int n_in,
                              void* d_out, int out_size, void* d_ws, size_t ws_size,
                              hipStream_t stream) {
    (void)in_sizes; (void)n_in; (void)d_ws; (void)ws_size;
    const float* x = (const float*)d_in[0];   // (1024, 784) float32 of 0/1
    const int*   w = (const int*)d_in[1];     // (1024, 32, 16) int32 in [0,1569)
    int* out = (int*)d_out;                   // (1024, 1024) bool -> int32

    fused5<<<512, 512, 0, stream>>>(x, w, out);
}